// Round 1
// 428.822 us; speedup vs baseline: 1.0077x; 1.0077x over previous
//
#include <hip/hip_runtime.h>

#define KCLS 19
#define NIMG 4
#define CCH  128
#define PPIX (256*512)   // 131072 pixels per image

// ---------------- workspace layout ----------------
// sums     [N][K][C]  float @ 0       (9728)   zeroed
// counts   [N][K]     float @ 9728    (76)     zeroed
// per_cls  [N][K]     float @ 9804    (76)     zeroed
// lab8     u8[N*PPIX]       @ byte 39520 (524288 B)  fully written by k_prep

// ---------- kernel 0: label convert (int32 -> u8) + histogram ----------
// Labels are re-read by every channel block; converting once to u8 cuts
// label traffic 4x and removes per-element histogram atomics from k_sums.
__global__ __launch_bounds__(256) void k_prep(const int* __restrict__ target,
                                              unsigned char* __restrict__ lab8,
                                              float* __restrict__ counts) {
  __shared__ int hist[KCLS];
  const int tid = threadIdx.x;
  const int n = blockIdx.x >> 3;      // 8 blocks per image
  const int q = blockIdx.x & 7;
  if (tid < KCLS) hist[tid] = 0;
  __syncthreads();
  const int* lab = target + (size_t)n*PPIX + q*(PPIX/8);
  unsigned char* l8 = lab8 + (size_t)n*PPIX + q*(PPIX/8);
  for (int i = tid*4; i < PPIX/8; i += 1024) {   // 16 iters
    const int4 v = *(const int4*)(lab + i);
    uchar4 u;
    u.x = (unsigned char)v.x; u.y = (unsigned char)v.y;
    u.z = (unsigned char)v.z; u.w = (unsigned char)v.w;
    *(uchar4*)(l8 + i) = u;
    if ((unsigned)v.x < KCLS) atomicAdd(&hist[v.x], 1);
    if ((unsigned)v.y < KCLS) atomicAdd(&hist[v.y], 1);
    if ((unsigned)v.z < KCLS) atomicAdd(&hist[v.z], 1);
    if ((unsigned)v.w < KCLS) atomicAdd(&hist[v.w], 1);
  }
  __syncthreads();
  if (tid < KCLS && hist[tid] > 0)
    atomicAdd(&counts[n*KCLS + tid], (float)hist[tid]);
}

// ---------- kernel 1: per-class feature sums (4 channels / block) ----------
// float4 lane-exclusive LDS columns: halves ds-RMW instruction count vs the
// float2 version and halves label re-reads (32 blocks/pixel instead of 64).
// LDS = 19*256*16 = 77824 B -> 2 blocks/CU, 8 waves/CU (streaming kernel,
// enough in-flight bytes to cover HBM latency).
__global__ __launch_bounds__(256) void k_sums(const float* __restrict__ predict,
                                              const unsigned char* __restrict__ lab8,
                                              float* __restrict__ sums) {
  __shared__ float4 cols[KCLS*256];   // 77824 B
  const int tid = threadIdx.x;
  const int n    = blockIdx.x >> 7;   // 128 blocks per image
  const int rem  = blockIdx.x & 127;
  const int cg   = rem >> 2;          // 32 channel groups of 4
  const int q    = rem & 3;           // pixel quarter
  const int c0   = cg * 4;

  for (int i = tid; i < KCLS*256; i += 256) cols[i] = make_float4(0.f,0.f,0.f,0.f);
  __syncthreads();

  const float* p0 = predict + ((size_t)n*CCH + c0) * PPIX;
  const unsigned char* lab = lab8 + (size_t)n*PPIX + q*(PPIX/4);
  const int base0 = q*(PPIX/4);

  for (int off = tid*4; off < PPIX/4; off += 1024) {   // 32 iters
    const int base = base0 + off;
    const uchar4  lb = *(const uchar4*)(lab + off);
    const float4 a = *(const float4*)(p0 + base);
    const float4 b = *(const float4*)(p0 + PPIX   + base);
    const float4 c = *(const float4*)(p0 + 2*PPIX + base);
    const float4 d = *(const float4*)(p0 + 3*PPIX + base);
    const unsigned kk[4] = {lb.x, lb.y, lb.z, lb.w};
    const float av[4] = {a.x, a.y, a.z, a.w};
    const float bv[4] = {b.x, b.y, b.z, b.w};
    const float cv[4] = {c.x, c.y, c.z, c.w};
    const float dv[4] = {d.x, d.y, d.z, d.w};
#pragma unroll
    for (int j = 0; j < 4; ++j) {
      const unsigned k = kk[j];
      if (k < KCLS) {
        float4* cp = &cols[k*256 + tid];
        cp->x += av[j];
        cp->y += bv[j];
        cp->z += cv[j];
        cp->w += dv[j];
      }
    }
  }
  __syncthreads();
  // tree-reduce 256 columns x 19 classes; flat index keeps all 8 waves busy
#pragma unroll
  for (int sh = 7; sh >= 0; --sh) {
    const int s = 1 << sh;
    for (int i = tid; i < KCLS*s; i += 256) {
      const int r   = i >> sh;
      const int col = i & (s - 1);
      float4* dst = &cols[r*256 + col];
      const float4 o = cols[r*256 + col + s];
      dst->x += o.x; dst->y += o.y; dst->z += o.z; dst->w += o.w;
    }
    __syncthreads();
  }
  if (tid < KCLS) {
    const float4 v = cols[tid*256];
    float* sp = &sums[((size_t)n*KCLS + tid)*CCH + c0];
    atomicAdd(sp + 0, v.x);
    atomicAdd(sp + 1, v.y);
    atomicAdd(sp + 2, v.z);
    atomicAdd(sp + 3, v.w);
  }
}

// ---------- kernel 2: loss_var pass (lean — no finalize) ----------
// Inline means from sums/counts (L2-hot), streaming distance pass over
// predict (second and last full read; partially L3-resident from pass 1).
__global__ __launch_bounds__(256) void k_var(const float* __restrict__ predict,
                                             const unsigned char* __restrict__ lab8,
                                             const float* __restrict__ sums,
                                             const float* __restrict__ counts,
                                             float* __restrict__ per_cls) {
  __shared__ float mT[CCH*20];        // [c][k] stride 20 -> conflict-free
  __shared__ float pc[KCLS];
  const int tid = threadIdx.x;
  const int n = blockIdx.x >> 7;
  const int tile = blockIdx.x & 127;

  for (int i = tid; i < KCLS*CCH; i += 256) {
    const int k = i >> 7, c = i & 127;
    mT[c*20 + k] = sums[n*KCLS*CCH + i] / fmaxf(counts[n*KCLS + k], 1.f);
  }
  if (tid < KCLS) pc[tid] = 0.f;

  const int p0 = tile*1024 + tid*4;
  const uchar4 lb = *(const uchar4*)(lab8 + (size_t)n*PPIX + p0);
  const unsigned u0 = min((unsigned)lb.x, (unsigned)(KCLS-1));
  const unsigned u1 = min((unsigned)lb.y, (unsigned)(KCLS-1));
  const unsigned u2 = min((unsigned)lb.z, (unsigned)(KCLS-1));
  const unsigned u3 = min((unsigned)lb.w, (unsigned)(KCLS-1));
  __syncthreads();

  float acc0 = 0.f, acc1 = 0.f, acc2 = 0.f, acc3 = 0.f;
  const float* gp = predict + (size_t)n*CCH*PPIX + p0;
#pragma unroll 8
  for (int c = 0; c < CCH; ++c) {
    const float4 v = *(const float4*)gp;
    gp += PPIX;
    const float* row = mT + c*20;
    const float d0 = row[u0] - v.x; acc0 = fmaf(d0, d0, acc0);
    const float d1 = row[u1] - v.y; acc1 = fmaf(d1, d1, acc1);
    const float d2 = row[u2] - v.z; acc2 = fmaf(d2, d2, acc2);
    const float d3 = row[u3] - v.w; acc3 = fmaf(d3, d3, acc3);
  }
  {
    float t;
    t = fmaxf(sqrtf(acc0) - 0.5f, 0.f); if ((unsigned)lb.x < KCLS) atomicAdd(&pc[lb.x], t*t);
    t = fmaxf(sqrtf(acc1) - 0.5f, 0.f); if ((unsigned)lb.y < KCLS) atomicAdd(&pc[lb.y], t*t);
    t = fmaxf(sqrtf(acc2) - 0.5f, 0.f); if ((unsigned)lb.z < KCLS) atomicAdd(&pc[lb.z], t*t);
    t = fmaxf(sqrtf(acc3) - 0.5f, 0.f); if ((unsigned)lb.w < KCLS) atomicAdd(&pc[lb.w], t*t);
  }
  __syncthreads();
  if (tid < KCLS) atomicAdd(&per_cls[n*KCLS + tid], pc[tid]);
}

// ---------- kernel 3: per-image finalize (4 blocks, atomic into out) ----------
__global__ __launch_bounds__(256) void k_final(const float* __restrict__ sums,
                                               const float* __restrict__ counts,
                                               const float* __restrict__ per_cls,
                                               float* __restrict__ out) {
  __shared__ float ml[KCLS*129];   // [k][c] stride 129 -> conflict-free
  __shared__ float sval[KCLS];
  __shared__ float red[256];
  const int tid = threadIdx.x;
  const int n = blockIdx.x;

  for (int i = tid; i < KCLS*CCH; i += 256) {
    const int k = i >> 7, c = i & 127;
    ml[k*129 + c] = sums[n*KCLS*CCH + i] / fmaxf(counts[n*KCLS + k], 1.f);
  }
  if (tid < KCLS) sval[tid] = (counts[n*KCLS + tid] > 20.f) ? 1.f : 0.f;
  __syncthreads();

  float s = 0.f;
  for (int k = 0; k < KCLS; ++k) s += sval[k];
  const float nv = fmaxf(s, 1.f);

  float local = 0.f;
  // loss_dis: ordered pairs f != s2, both valid
  for (int pr = tid; pr < KCLS*KCLS; pr += 256) {
    const int f = pr / KCLS, s2 = pr % KCLS;
    if (f != s2 && sval[f] > 0.f && sval[s2] > 0.f) {
      const float* mf = ml + f*129;
      const float* ms = ml + s2*129;
      float acc = 0.f;
      for (int c = 0; c < CCH; ++c) {
        const float d = mf[c] - ms[c];
        acc = fmaf(d, d, acc);
      }
      const float t = fmaxf(3.0f - sqrtf(acc), 0.f);   // 2*DELTA = 3
      local += t * t / fmaxf(nv*(nv - 1.f), 1.f);
    }
  }
  // loss_reg + loss_var terms
  if (tid < KCLS && sval[tid] > 0.f) {
    const float* m = ml + tid*129;
    float acc = 0.f;
    for (int c = 0; c < CCH; ++c) acc = fmaf(m[c], m[c], acc);
    local += 0.001f * sqrtf(acc) / nv;
    local += (per_cls[n*KCLS + tid] / fmaxf(counts[n*KCLS + tid], 1.f)) / nv;
  }

  red[tid] = local;
  __syncthreads();
  for (int s3 = 128; s3 >= 1; s3 >>= 1) {
    if (tid < s3) red[tid] += red[tid + s3];
    __syncthreads();
  }
  if (tid == 0) atomicAdd(out, 0.25f * red[0]);   // mean over NIMG=4
}

extern "C" void kernel_launch(void* const* d_in, const int* in_sizes, int n_in,
                              void* d_out, int out_size, void* d_ws, size_t ws_size,
                              hipStream_t stream) {
  const float* predict = (const float*)d_in[0];
  const int*   target  = (const int*)d_in[1];
  float* out = (float*)d_out;
  float* ws  = (float*)d_ws;

  float* sums    = ws;            // 9728
  float* counts  = ws + 9728;     // 76
  float* per_cls = ws + 9804;     // 76
  unsigned char* lab8 = (unsigned char*)(ws + 9880);   // byte 39520, 16B-aligned

  // zero accumulators (ws is poisoned 0xAA) and out (k_final accumulates)
  hipMemsetAsync(ws, 0, (size_t)9880 * sizeof(float), stream);
  hipMemsetAsync(out, 0, sizeof(float), stream);

  k_prep <<<NIMG*8,   256, 0, stream>>>(target, lab8, counts);
  k_sums <<<NIMG*128, 256, 0, stream>>>(predict, lab8, sums);
  k_var  <<<NIMG*128, 256, 0, stream>>>(predict, lab8, sums, counts, per_cls);
  k_final<<<NIMG,     256, 0, stream>>>(sums, counts, per_cls, out);
}